// Round 1
// baseline (86.665 us; speedup 1.0000x reference)
//
#include <hip/hip_runtime.h>
#include <math.h>

#define C_DIM 128
#define H_DIM 128
#define W_DIM 128
#define HW (H_DIM * W_DIM)
#define TW 64
#define TH 4
#define HCW (TW + 2)        // 66
#define HCH (TH + 2)        // 6
#define NH (HCW * HCH)      // 396
#define NT 256
#define EPS_N 1e-12f

// One thread = one output pixel. Two channel passes:
//  pass 1: accumulate 9 neighbor dots + ||fused[nb]||^2 (LDS) + ||fe||^2 (reg)
//  softmax over 9 cosines (OOB neighbors contribute cos = 0 exactly)
//  pass 2: out[c] = sum_k w_k * fused[c, nb_k] + fe[c]
// Channels processed 2 per iteration with register prefetch of the next pair.
__global__ __launch_bounds__(NT) void asfr_fused(
    const float* __restrict__ fe,
    const float* __restrict__ fu,
    float* __restrict__ out)
{
    __shared__ float ha[NH];   // halo, channel 2i
    __shared__ float hb[NH];   // halo, channel 2i+1
    __shared__ float nf2[NH];  // sum of squares per halo pixel -> later 1/norm

    const int tid = threadIdx.x;
    const int tx = tid & (TW - 1);
    const int ty = tid >> 6;
    const int bx = blockIdx.x, by = blockIdx.y, bz = blockIdx.z;
    const int col = bx * TW + tx;
    const int row = by * TH + ty;
    const int pix = row * W_DIM + col;
    const size_t imgbase = (size_t)bz * C_DIM * HW;

    // halo elements owned by this thread: i0 = tid, i1 = tid + 256 (if < 396)
    const int i0 = tid;
    const int hr0 = i0 / HCW, hc0 = i0 - hr0 * HCW;
    const int gr0 = by * TH + hr0 - 1, gc0 = bx * TW + hc0 - 1;
    const bool v0 = (gr0 >= 0 && gr0 < H_DIM && gc0 >= 0 && gc0 < W_DIM);
    const float* p0 = fu + imgbase + (v0 ? (gr0 * W_DIM + gc0) : 0);

    const int i1 = tid + NT;
    const bool has1 = (i1 < NH);
    const int hr1 = i1 / HCW, hc1 = i1 - hr1 * HCW;
    const int gr1 = by * TH + hr1 - 1, gc1 = bx * TW + hc1 - 1;
    const bool v1 = has1 && (gr1 >= 0 && gr1 < H_DIM && gc1 >= 0 && gc1 < W_DIM);
    const float* p1 = fu + imgbase + (v1 ? (gr1 * W_DIM + gc1) : 0);

    const float* pfe = fe + imgbase + pix;
    float* pout = out + imgbase + pix;

    nf2[i0] = 0.f;
    if (has1) nf2[i1] = 0.f;

    float dot[9];
#pragma unroll
    for (int k = 0; k < 9; ++k) dot[k] = 0.f;
    float ne2 = 0.f;

    // prefetch channel pair 0
    float a0  = v0 ? p0[0]  : 0.f;
    float b0v = v0 ? p0[HW] : 0.f;
    float a1  = v1 ? p1[0]  : 0.f;
    float b1v = v1 ? p1[HW] : 0.f;
    float fa = pfe[0];
    float fb = pfe[HW];

    // ---------------- pass 1: dots + norms ----------------
    for (int ci = 0; ci < C_DIM / 2; ++ci) {
        ha[i0] = a0; hb[i0] = b0v;
        nf2[i0] += a0 * a0 + b0v * b0v;
        if (has1) { ha[i1] = a1; hb[i1] = b1v; nf2[i1] += a1 * a1 + b1v * b1v; }
        const float fa_c = fa, fb_c = fb;
        __syncthreads();
        if (ci + 1 < C_DIM / 2) {   // prefetch next channel pair (hides HBM latency)
            const size_t off = (size_t)(2 * (ci + 1)) * HW;
            a0  = v0 ? p0[off]      : 0.f;
            b0v = v0 ? p0[off + HW] : 0.f;
            a1  = v1 ? p1[off]      : 0.f;
            b1v = v1 ? p1[off + HW] : 0.f;
            fa = pfe[off];
            fb = pfe[off + HW];
        }
        ne2 += fa_c * fa_c + fb_c * fb_c;
#pragma unroll
        for (int di = 0; di < 3; ++di)
#pragma unroll
            for (int dj = 0; dj < 3; ++dj) {
                const int idx = (ty + di) * HCW + (tx + dj);
                dot[di * 3 + dj] += ha[idx] * fa_c + hb[idx] * fb_c;
            }
        __syncthreads();
    }

    // convert nf2 -> reciprocal clamped norms (in place, owner-only)
    {
        const float n0 = sqrtf(nf2[i0]);
        nf2[i0] = 1.f / fmaxf(n0, EPS_N);
        if (has1) {
            const float n1 = sqrtf(nf2[i1]);
            nf2[i1] = 1.f / fmaxf(n1, EPS_N);
        }
    }
    const float rne = 1.f / fmaxf(sqrtf(ne2), EPS_N);
    __syncthreads();

    // ---------------- softmax over the 9 cosines ----------------
    float w[9];
    float m = -1e30f;
#pragma unroll
    for (int di = 0; di < 3; ++di)
#pragma unroll
        for (int dj = 0; dj < 3; ++dj) {
            const int k = di * 3 + dj;
            const float cosv = dot[k] * nf2[(ty + di) * HCW + (tx + dj)] * rne;
            w[k] = cosv;
            m = fmaxf(m, cosv);
        }
    float s = 0.f;
#pragma unroll
    for (int k = 0; k < 9; ++k) { w[k] = __expf(w[k] - m); s += w[k]; }
    const float inv_s = 1.f / s;
#pragma unroll
    for (int k = 0; k < 9; ++k) w[k] *= inv_s;

    // prefetch pair 0 for pass 2 (re-reads are L2/L3 hits)
    a0  = v0 ? p0[0]  : 0.f;
    b0v = v0 ? p0[HW] : 0.f;
    a1  = v1 ? p1[0]  : 0.f;
    b1v = v1 ? p1[HW] : 0.f;
    fa = pfe[0];
    fb = pfe[HW];

    // ---------------- pass 2: weighted aggregation ----------------
    for (int ci = 0; ci < C_DIM / 2; ++ci) {
        ha[i0] = a0; hb[i0] = b0v;
        if (has1) { ha[i1] = a1; hb[i1] = b1v; }
        const float fa_c = fa, fb_c = fb;
        __syncthreads();
        if (ci + 1 < C_DIM / 2) {
            const size_t off = (size_t)(2 * (ci + 1)) * HW;
            a0  = v0 ? p0[off]      : 0.f;
            b0v = v0 ? p0[off + HW] : 0.f;
            a1  = v1 ? p1[off]      : 0.f;
            b1v = v1 ? p1[off + HW] : 0.f;
            fa = pfe[off];
            fb = pfe[off + HW];
        }
        float acca = 0.f, accb = 0.f;
#pragma unroll
        for (int di = 0; di < 3; ++di)
#pragma unroll
            for (int dj = 0; dj < 3; ++dj) {
                const int idx = (ty + di) * HCW + (tx + dj);
                const float wk = w[di * 3 + dj];
                acca += wk * ha[idx];
                accb += wk * hb[idx];
            }
        const size_t offc = (size_t)(2 * ci) * HW;
        pout[offc]      = acca + fa_c;
        pout[offc + HW] = accb + fb_c;
        __syncthreads();
    }
}

extern "C" void kernel_launch(void* const* d_in, const int* in_sizes, int n_in,
                              void* d_out, int out_size, void* d_ws, size_t ws_size,
                              hipStream_t stream) {
    const float* fe = (const float*)d_in[0];   // fe_lv
    const float* fu = (const float*)d_in[1];   // fused_features
    float* out = (float*)d_out;
    const int B = in_sizes[0] / (C_DIM * HW);
    dim3 grid(W_DIM / TW, H_DIM / TH, B);
    dim3 block(NT);
    asfr_fused<<<grid, block, 0, stream>>>(fe, fu, out);
}

// Round 2
// 49.646 us; speedup vs baseline: 1.7457x; 1.7457x over previous
//
#include <hip/hip_runtime.h>
#include <math.h>

#define C_DIM 128
#define H_DIM 128
#define W_DIM 128
#define HW (H_DIM * W_DIM)
#define EPS_N 1e-12f
#define NT 256
#define PX 32              // pixels per block (contiguous along W)
#define NG 8               // channel groups
#define CPG (C_DIM / NG)   // 16 channels per group
#define BPI (HW / PX)      // 512 blocks per image
#define SEGS (W_DIM / PX)  // 4 col segments per row

// ---------------- kernel 1: reciprocal clamped L2 norm of fused over C ----------------
__global__ __launch_bounds__(NT) void norms_fu(const float* __restrict__ fu,
                                               float* __restrict__ rn)
{
    __shared__ float part[PX * 9];  // [px][g] padded stride 9 (conflict-free)
    const int tid = threadIdx.x;
    const int px = tid & (PX - 1);
    const int g = tid >> 5;
    const int n = blockIdx.x * PX + px;
    const float* p = fu + (size_t)blockIdx.y * C_DIM * HW + (size_t)g * CPG * HW + n;
    float s = 0.f;
#pragma unroll
    for (int j = 0; j < CPG; ++j) {
        const float v = p[(size_t)j * HW];
        s += v * v;
    }
    part[px * 9 + g] = s;
    __syncthreads();
    if (tid < PX) {
        float t = 0.f;
#pragma unroll
        for (int gg = 0; gg < NG; ++gg) t += part[tid * 9 + gg];
        rn[(size_t)blockIdx.y * HW + blockIdx.x * PX + tid] =
            1.f / fmaxf(sqrtf(t), EPS_N);
    }
}

// ---------------- kernel 2: dots + softmax + weighted aggregation ----------------
__global__ __launch_bounds__(NT) void asfr_main(const float* __restrict__ fe,
                                                const float* __restrict__ fu,
                                                const float* __restrict__ rn,
                                                float* __restrict__ out)
{
    __shared__ float part[PX * 10 * 9];  // [v=p*10+k][g], pad 9 → conflict-free reduce
    __shared__ float red[PX * 10];       // reduced: 9 dots + fe2 per pixel
    __shared__ float wl[PX * 10];        // softmax weights [p][k], pad 10

    const int tid = threadIdx.x;
    const int px = tid & (PX - 1);
    const int g = tid >> 5;

    // XCD-chunked bijective swizzle (gridDim.x = 2048, % 8 == 0)
    const int bid = blockIdx.x;
    const int cpx = gridDim.x >> 3;
    const int wb = (bid & 7) * cpx + (bid >> 3);

    const int bz = wb / BPI;
    const int rem = wb - bz * BPI;
    const int row = rem / SEGS;
    const int seg = rem - row * SEGS;
    const int col = seg * PX + px;
    const int n = row * W_DIM + col;
    const size_t imgbase = (size_t)bz * C_DIM * HW;

    const float* pfe = fe + imgbase + (size_t)g * CPG * HW + n;
    const float* pfu = fu + imgbase + (size_t)g * CPG * HW + n;

    // neighbor validity + safe offsets (compile-time dr/dc)
    bool ok[9];
    int sdel[9];
#pragma unroll
    for (int k = 0; k < 9; ++k) {
        const int dr = k / 3 - 1, dc = k % 3 - 1;
        const int nr = row + dr, nc = col + dc;
        ok[k] = (nr >= 0 && nr < H_DIM && nc >= 0 && nc < W_DIM);
        sdel[k] = ok[k] ? (dr * W_DIM + dc) : 0;
    }

    // ---------- phase 1: partial dots + partial ||fe||^2 ----------
    float d[9] = {0.f, 0.f, 0.f, 0.f, 0.f, 0.f, 0.f, 0.f, 0.f};
    float fe2 = 0.f;
#pragma unroll 4
    for (int j = 0; j < CPG; ++j) {
        const float fv = pfe[(size_t)j * HW];
        fe2 += fv * fv;
        const float* q = pfu + (size_t)j * HW;
#pragma unroll
        for (int k = 0; k < 9; ++k) {
            const float v = ok[k] ? q[sdel[k]] : 0.f;
            d[k] += fv * v;
        }
    }
#pragma unroll
    for (int k = 0; k < 9; ++k) part[(px * 10 + k) * 9 + g] = d[k];
    part[(px * 10 + 9) * 9 + g] = fe2;
    __syncthreads();

    // ---------- tree reduce over the 8 groups ----------
    for (int v = tid; v < PX * 10; v += NT) {
        float s = 0.f;
#pragma unroll
        for (int gg = 0; gg < NG; ++gg) s += part[v * 9 + gg];
        red[v] = s;
    }
    __syncthreads();

    // ---------- softmax weights (one thread per pixel) ----------
    if (tid < PX) {
        const int p = tid;  // this thread's px == p, so ok[]/n refer to its pixel
        const float rfe = 1.f / fmaxf(sqrtf(red[p * 10 + 9]), EPS_N);
        float c[9];
        float m = -1e30f;
#pragma unroll
        for (int k = 0; k < 9; ++k) {
            const int dr = k / 3 - 1, dc = k % 3 - 1;
            float cv = 0.f;
            if (ok[k])
                cv = red[p * 10 + k] * rfe *
                     rn[(size_t)bz * HW + n + dr * W_DIM + dc];
            c[k] = cv;
            m = fmaxf(m, cv);
        }
        float s = 0.f;
#pragma unroll
        for (int k = 0; k < 9; ++k) { c[k] = __expf(c[k] - m); s += c[k]; }
        const float is = 1.f / s;
#pragma unroll
        for (int k = 0; k < 9; ++k) wl[p * 10 + k] = c[k] * is;
    }
    __syncthreads();

    // ---------- phase 2: weighted 3x3 gather + residual ----------
    float w[9];
#pragma unroll
    for (int k = 0; k < 9; ++k) w[k] = wl[px * 10 + k];

    float* pout = out + imgbase + (size_t)g * CPG * HW + n;
#pragma unroll 4
    for (int j = 0; j < CPG; ++j) {
        const float fv = pfe[(size_t)j * HW];
        const float* q = pfu + (size_t)j * HW;
        float acc = fv;
#pragma unroll
        for (int k = 0; k < 9; ++k) {
            const float v = ok[k] ? q[sdel[k]] : 0.f;
            acc += w[k] * v;
        }
        pout[(size_t)j * HW] = acc;
    }
}

extern "C" void kernel_launch(void* const* d_in, const int* in_sizes, int n_in,
                              void* d_out, int out_size, void* d_ws, size_t ws_size,
                              hipStream_t stream) {
    const float* fe = (const float*)d_in[0];   // fe_lv
    const float* fu = (const float*)d_in[1];   // fused_features
    float* out = (float*)d_out;
    float* rn = (float*)d_ws;                  // B*HW floats (256 KB for B=4)
    const int B = in_sizes[0] / (C_DIM * HW);

    dim3 g1(HW / PX, B);
    norms_fu<<<g1, NT, 0, stream>>>(fu, rn);

    dim3 g2(B * BPI);
    asfr_main<<<g2, NT, 0, stream>>>(fe, fu, rn, out);
}